// Round 1
// 714.322 us; speedup vs baseline: 1.0359x; 1.0359x over previous
//
#include <hip/hip_runtime.h>

typedef unsigned short u16;
typedef unsigned int u32;
typedef __bf16 bf16x8 __attribute__((ext_vector_type(8)));
typedef float f32x4 __attribute__((ext_vector_type(4)));

#define BB   2
#define SS   2048
#define EE   2048
#define HH   2688
#define NHH  4
#define DHH  672
#define NPHH 672
#define H2   5376
#define H3   8064

__device__ __forceinline__ float b2f(u16 u) {
  union { unsigned int i; float f; } c; c.i = ((unsigned int)u) << 16; return c.f;
}
__device__ __forceinline__ u16 f2b(float f) {
  union { float f; unsigned int i; } c; c.f = f;
  unsigned int i = c.i;
  return (u16)((i + 0x7FFFu + ((i >> 16) & 1u)) >> 16);
}
__device__ __forceinline__ float silu_f(float x) { return x / (1.f + __expf(-x)); }
__device__ __forceinline__ float logsig_f(float f) {
  return (f >= 0.f) ? -log1pf(__expf(-f)) : (f - log1pf(__expf(f)));
}

// async global->LDS, 16B per lane; dst wave-uniform base, HW adds lane*16B
__device__ __forceinline__ void gl2lds16(const u16* g, u16* s) {
  __builtin_amdgcn_global_load_lds(
      (const __attribute__((address_space(1))) u32*)g,
      (__attribute__((address_space(3))) u32*)s, 16, 0, 0);
}

// ---------------------------------------------------------------------------
// Deep-pipelined NT GEMM (bf16): C[i,j] = sum_k A[i,k]*Bt[j,k]
// 128x256 tile, BK=32, 8 waves, 4-deep LDS ring buffer, stage lead = 3 tiles,
// counted s_waitcnt vmcnt(6) (never 0 mid-loop), raw s_barrier, setprio(1)
// around the MFMA cluster, XOR bank-swizzle via pre-swizzled global source
// (involution s ^= (row>>1)&3 on 16B chunks), bijective XCD block swizzle.
// MODE 0 plain; MODE 1 QK epilogue (skip above-diag blocks);
// MODE 2 PV epilogue (row scale, causal K-cap). OUTF32: fp32 store.
// Requires: M % 128 == 0, K % 32 == 0. N bounds-checked on store; B staging
// may over-read up to 255 rows past N (callers guarantee in-bounds memory).
// ---------------------------------------------------------------------------
template <int MODE, int OUTF32>
__global__ __launch_bounds__(512, 2) void gemm_nt2(
    const u16* __restrict__ A, const u16* __restrict__ Bt, void* __restrict__ Cp,
    int M, int N, int K, int lda, int ldb, int ldc,
    long sAhi, long sAlo, long sBhi, long sBlo, long sChi, long sClo,
    const float* __restrict__ aux1, const float* __restrict__ aux2,
    int auxStride, int causal)
{
  // 4 ring buffers x (A 128x32 | B 256x32) bf16 = 4 x 24 KiB = 96 KiB
  __shared__ __align__(16) u16 sm[4 * 12288];

  // bijective XCD-aware block swizzle (all grids here have nwg % 8 == 0)
  int gx = gridDim.x;
  int nwg = gx * gridDim.y;
  int flat = blockIdx.y * gx + blockIdx.x;
  int qq = nwg >> 3, r8 = nwg & 7;
  int xcd = flat & 7, seq = flat >> 3;
  int logical = (xcd < r8 ? xcd * (qq + 1) : r8 * (qq + 1) + (xcd - r8) * qq) + seq;
  int bx = logical % gx, by = logical / gx;
  int m0 = by * 128, n0 = bx * 256;
  if (MODE == 1 && n0 > m0 + 127) return;

  int bz = blockIdx.z, bzh = bz >> 2, bzl = bz & 3;
  A  += bzh * sAhi + bzl * sAlo;
  Bt += bzh * sBhi + bzl * sBlo;
  const float* a1 = aux1 ? aux1 + (long)bz * auxStride : nullptr;
  const float* a2 = aux2 ? aux2 + (long)bz * auxStride : nullptr;
  u16*   C16 = (u16*)Cp + bzh * sChi + bzl * sClo;
  float* C32 = (float*)Cp + bzh * sChi + bzl * sClo;

  int t = threadIdx.x, lane = t & 63, w = t >> 6;
  int l15 = lane & 15, quad = lane >> 4;
  int wr = w >> 2, wc = w & 3;   // wave -> (M half, N quarter)

  // staging: pre-swizzled global source. chunk s_phys at row gets logical
  // chunk s_phys ^ ((row>>1)&3); for our lane mapping that is
  // (lane&3) ^ ((lane>>3)&3)  (w contributes 0 mod 4 in all cases).
  int sx8 = ((lane & 3) ^ ((lane >> 3) & 3)) * 8;
  const u16* pA  = A  + (long)(m0 + w * 16 + (lane >> 2)) * lda + sx8;
  const u16* pB0 = Bt + (long)(n0 + w * 32 + (lane >> 2)) * ldb + sx8;
  const u16* pB1 = pB0 + (long)16 * ldb;
  u16* dA  = sm + w * 512;
  u16* dB0 = sm + 4096 + w * 1024;
  u16* dB1 = dB0 + 512;

  // swizzled read column: same involution, rows differ only in l15 bits mod 4
  int sxr = (quad ^ ((l15 >> 1) & 3)) * 8;
  int aoff = (wr * 64 + l15) * 32 + sxr;          // + i*512 per 16-row frag
  int boff = 4096 + (wc * 64 + l15) * 32 + sxr;   // + j*512

  f32x4 acc[4][4];
#pragma unroll
  for (int i = 0; i < 4; i++)
#pragma unroll
    for (int j = 0; j < 4; j++) acc[i][j] = (f32x4){0.f, 0.f, 0.f, 0.f};

  int Keff = (MODE == 2 && causal) ? min(K, m0 + 128) : K;
  int T = Keff >> 5;

  auto STAGE = [&](int tt) {
    int bo = (tt & 3) * 12288;
    int k2 = tt << 5;
    gl2lds16(pA + k2, dA + bo);
    gl2lds16(pB0 + k2, dB0 + bo);
    gl2lds16(pB1 + k2, dB1 + bo);
  };

  // prologue: stage tiles 0..2 (9 loads/thread), wait for tile 0 only
  int npre = T < 3 ? T : 3;
  for (int tt = 0; tt < npre; ++tt) STAGE(tt);
  if (npre >= 3)      asm volatile("s_waitcnt vmcnt(6)" ::: "memory");
  else if (npre == 2) asm volatile("s_waitcnt vmcnt(3)" ::: "memory");
  else                asm volatile("s_waitcnt vmcnt(0)" ::: "memory");
  __builtin_amdgcn_s_barrier();
  __builtin_amdgcn_sched_barrier(0);

  for (int tq = 0; tq < T; ++tq) {
    const u16* Ab = sm + (tq & 3) * 12288;
    bf16x8 af[4], bfr[4];
#pragma unroll
    for (int i = 0; i < 4; i++) {
      af[i]  = *reinterpret_cast<const bf16x8*>(&Ab[aoff + i * 512]);
      bfr[i] = *reinterpret_cast<const bf16x8*>(&Ab[boff + i * 512]);
    }
    if (tq + 3 < T) STAGE(tq + 3);   // ring buf (tq+3)&3: not read this tile
    __builtin_amdgcn_s_barrier();
    __builtin_amdgcn_s_setprio(1);
#pragma unroll
    for (int i = 0; i < 4; i++)
#pragma unroll
      for (int j = 0; j < 4; j++)
        acc[i][j] = __builtin_amdgcn_mfma_f32_16x16x32_bf16(af[i], bfr[j], acc[i][j], 0, 0, 0);
    __builtin_amdgcn_s_setprio(0);
    // boundary wait: everything older than the newest {t+2,t+3} stages is done
    int rem = T - 1 - tq;
    if (rem >= 3)      asm volatile("s_waitcnt vmcnt(6)" ::: "memory");
    else if (rem == 2) asm volatile("s_waitcnt vmcnt(3)" ::: "memory");
    else if (rem == 1) asm volatile("s_waitcnt vmcnt(0)" ::: "memory");
    __builtin_amdgcn_s_barrier();
    __builtin_amdgcn_sched_barrier(0);
  }

  const float rs = 0.03857583749f;  // 1/sqrt(672)
#pragma unroll
  for (int i = 0; i < 4; i++) {
#pragma unroll
    for (int j = 0; j < 4; j++) {
      int col = n0 + wc * 64 + j * 16 + l15;
      if (col >= N) continue;
#pragma unroll
      for (int rr = 0; rr < 4; rr++) {
        int row = m0 + wr * 64 + i * 16 + quad * 4 + rr;
        if (row >= M) continue;
        float v = acc[i][j][rr];
        if (MODE == 1) v = (col <= row) ? v * rs * __expf(a1[col] - a2[row]) : 0.f;
        else if (MODE == 2) v = v * a1[row];
        if (OUTF32) C32[(long)row * ldc + col] = v;
        else        C16[(long)row * ldc + col] = f2b(v);
      }
    }
  }
}

// ---------------------------------------------------------------------------
// Old 128x128 NT GEMM — kept only for the tiny N=24 gates GEMM.
// ---------------------------------------------------------------------------
template <int MODE, int OUTF32>
__global__ __launch_bounds__(256) void gemm_nt(
    const u16* __restrict__ A, const u16* __restrict__ Bt, void* __restrict__ Cp,
    int M, int N, int K, int lda, int ldb, int ldc,
    long sAhi, long sAlo, long sBhi, long sBlo, long sChi, long sClo,
    const float* __restrict__ aux1, const float* __restrict__ aux2,
    int auxStride, int causal)
{
  __shared__ __align__(16) u16 As[128 * 32];
  __shared__ __align__(16) u16 Bs[128 * 32];
  int m0 = blockIdx.y * 128, n0 = blockIdx.x * 128;
  if (MODE == 1 && n0 > m0 + 127) return;
  int bz = blockIdx.z, bzh = bz >> 2, bzl = bz & 3;
  A  += bzh * sAhi + bzl * sAlo;
  Bt += bzh * sBhi + bzl * sBlo;
  const float* a1 = aux1 ? aux1 + (long)bz * auxStride : nullptr;
  const float* a2 = aux2 ? aux2 + (long)bz * auxStride : nullptr;
  u16*   C16 = (u16*)Cp + bzh * sChi + bzl * sClo;
  float* C32 = (float*)Cp + bzh * sChi + bzl * sClo;

  int t = threadIdx.x, lane = t & 63, wid = t >> 6;
  int wm = (wid >> 1) * 64, wn = (wid & 1) * 64;
  int l15 = lane & 15, quad = lane >> 4;

  int srow = wid * 16 + (lane >> 2);
  int scol = (lane & 3) * 8;
  const u16* pA0 = A + (long)(m0 + srow) * lda + scol;
  const u16* pA1 = pA0 + (long)64 * lda;
  const u16* pB0 = Bt + (long)(n0 + srow) * ldb + scol;
  const u16* pB1 = pB0 + (long)64 * ldb;
  u16* dA = As + wid * 512;
  u16* dB = Bs + wid * 512;

  f32x4 acc[4][4];
#pragma unroll
  for (int i = 0; i < 4; i++)
#pragma unroll
    for (int j = 0; j < 4; j++) acc[i][j] = (f32x4){0.f, 0.f, 0.f, 0.f};

  int Keff = (MODE == 2 && causal) ? min(K, m0 + 128) : K;

  for (int k0 = 0; k0 < Keff; k0 += 32) {
    __syncthreads();
    gl2lds16(pA0 + k0, dA);
    gl2lds16(pA1 + k0, dA + 2048);
    gl2lds16(pB0 + k0, dB);
    gl2lds16(pB1 + k0, dB + 2048);
    __syncthreads();
    bf16x8 af[4], bfr[4];
#pragma unroll
    for (int i = 0; i < 4; i++) {
      af[i]  = *reinterpret_cast<const bf16x8*>(&As[(wm + i * 16 + l15) * 32 + quad * 8]);
      bfr[i] = *reinterpret_cast<const bf16x8*>(&Bs[(wn + i * 16 + l15) * 32 + quad * 8]);
    }
#pragma unroll
    for (int i = 0; i < 4; i++)
#pragma unroll
      for (int j = 0; j < 4; j++)
        acc[i][j] = __builtin_amdgcn_mfma_f32_16x16x32_bf16(af[i], bfr[j], acc[i][j], 0, 0, 0);
  }

  const float rs = 0.03857583749f;  // 1/sqrt(672)
#pragma unroll
  for (int i = 0; i < 4; i++) {
#pragma unroll
    for (int j = 0; j < 4; j++) {
      int col = n0 + wn + j * 16 + l15;
      if (col >= N) continue;
#pragma unroll
      for (int rr = 0; rr < 4; rr++) {
        int row = m0 + wm + i * 16 + quad * 4 + rr;
        if (row >= M) continue;
        float v = acc[i][j][rr];
        if (MODE == 1) v = (col <= row) ? v * rs * __expf(a1[col] - a2[row]) : 0.f;
        else if (MODE == 2) v = v * a1[row];
        if (OUTF32) C32[(long)row * ldc + col] = v;
        else        C16[(long)row * ldc + col] = f2b(v);
      }
    }
  }
}

// ---------------------------------------------------------------------------
// transpose with row stride: out[c*R + r] = in[r*ldin + c]; F32IN: fp32 source
// ---------------------------------------------------------------------------
template <int F32IN>
__global__ __launch_bounds__(256) void transpose_any(
    const void* __restrict__ in, u16* __restrict__ out, int R, int C, int ldin,
    long inHi, long inLo, long outStride)
{
  __shared__ u16 tile[64][65];
  int bz = blockIdx.z, bzh = bz >> 2, bzl = bz & 3;
  const u16* in16 = (const u16*)in + bzh * inHi + bzl * inLo;
  const float* inf = (const float*)in + bzh * inHi + bzl * inLo;
  out += (long)bz * outStride;
  int r0 = blockIdx.y * 64, c0 = blockIdx.x * 64;
  int t = threadIdx.x;
  for (int idx = t; idx < 64 * 64; idx += 256) {
    int r = idx >> 6, c = idx & 63;
    int rr = r0 + r, cc = c0 + c;
    u16 v = 0;
    if (rr < R && cc < C) {
      long off = (long)rr * ldin + cc;
      v = F32IN ? f2b(inf[off]) : in16[off];
    }
    tile[r][c] = v;
  }
  __syncthreads();
  for (int idx = t; idx < 64 * 64; idx += 256) {
    int r = idx & 63, c = idx >> 6;
    int rr = r0 + r, cc = c0 + c;
    if (rr < R && cc < C) out[(long)cc * R + rr] = tile[r][c];
  }
}

// ---------------------------------------------------------------------------
// x fp32 -> bf16, 8/thread
__global__ __launch_bounds__(256) void convert_x(
    const float* __restrict__ x, u16* __restrict__ o)
{
  long i = ((long)blockIdx.x * 256 + threadIdx.x) * 8;
  if (i >= (long)4096 * EE) return;
  float4 a = *reinterpret_cast<const float4*>(x + i);
  float4 b = *reinterpret_cast<const float4*>(x + i + 4);
  u16 t8[8] = {f2b(a.x), f2b(a.y), f2b(a.z), f2b(a.w),
               f2b(b.x), f2b(b.y), f2b(b.z), f2b(b.w)};
  *reinterpret_cast<uint4*>(o + i) = *reinterpret_cast<uint4*>(t8);
}

// ---------------------------------------------------------------------------
// WT3 (128 x 2688 bf16): rows r<24: r=seg*8+j -> (j<4?W_ig:W_fg)[seg*H + c, j&3]
__global__ __launch_bounds__(256) void prep_wt3(
    const float* __restrict__ Wig, const float* __restrict__ Wfg,
    u16* __restrict__ WT3)
{
  int i = blockIdx.x * 256 + threadIdx.x;
  if (i >= 128 * HH) return;
  int r = i / HH, c = i % HH;
  float v = 0.f;
  if (r < 24) {
    int seg = r >> 3, j = r & 7;
    const float* W = (j < 4) ? Wig : Wfg;
    v = W[(long)(seg * HH + c) * 4 + (j & 3)];
  }
  WT3[i] = f2b(v);
}

// Wq|Wk|Wv fp32 -> bf16 packed (3 x 10752)
__global__ __launch_bounds__(256) void prep_wqkv(
    const float* __restrict__ Wq, const float* __restrict__ Wk,
    const float* __restrict__ Wv, u16* __restrict__ o)
{
  int i = blockIdx.x * 256 + threadIdx.x;
  if (i >= 3 * 10752) return;
  int m = i / 10752, j = i % 10752;
  const float* W = (m == 0) ? Wq : (m == 1) ? Wk : Wv;
  o[i] = f2b(W[j]);
}

// ---------------------------------------------------------------------------
// depthwise causal conv (KS=4) + bias + silu, 4 h/thread
__global__ __launch_bounds__(256) void conv_silu(
    const u16* __restrict__ xinner, const float* __restrict__ cw,
    const float* __restrict__ cb, u16* __restrict__ xca)
{
  long idx = (long)blockIdx.x * 256 + threadIdx.x;
  if (idx >= (long)BB * SS * HH / 4) return;
  int h4 = (int)(idx % (HH / 4)) * 4;
  long bs = idx / (HH / 4);
  int s = (int)(bs % SS);
  float4 acc = *reinterpret_cast<const float4*>(cb + h4);
#pragma unroll
  for (int w = 0; w < 4; w++) {
    int sp = s + w - 3;
    if (sp < 0) continue;
    uint2 xr = *reinterpret_cast<const uint2*>(xinner + (bs + w - 3) * H2 + h4);
    const u16* xh = (const u16*)&xr;
    float4 cwv = *reinterpret_cast<const float4*>(cw + w * HH + h4);
    acc.x += b2f(xh[0]) * cwv.x;
    acc.y += b2f(xh[1]) * cwv.y;
    acc.z += b2f(xh[2]) * cwv.z;
    acc.w += b2f(xh[3]) * cwv.w;
  }
  u16 o4[4] = {f2b(silu_f(acc.x)), f2b(silu_f(acc.y)),
               f2b(silu_f(acc.z)), f2b(silu_f(acc.w))};
  *reinterpret_cast<uint2*>(xca + bs * HH + h4) = *reinterpret_cast<uint2*>(o4);
}

// ---------------------------------------------------------------------------
// headwise 4x4 projections, outputs stay in (B,S,H) layout (no relayout)
__global__ __launch_bounds__(256) void headwise_qkv(
    const u16* __restrict__ xinner, const u16* __restrict__ xca,
    const u16* __restrict__ Wqkv,
    u16* __restrict__ q, u16* __restrict__ k, u16* __restrict__ v)
{
  int idx = blockIdx.x * 256 + threadIdx.x;
  if (idx >= BB * SS * NPHH) return;
  int nph = idx % NPHH;
  long bs = idx / NPHH;
  int cbase = nph * 4;
  uint2 xar = *reinterpret_cast<const uint2*>(xca + bs * HH + cbase);
  uint2 xmr = *reinterpret_cast<const uint2*>(xinner + bs * H2 + cbase);
  const u16* xa = (const u16*)&xar;
  const u16* xm = (const u16*)&xmr;
  float xaf[4], xmf[4];
#pragma unroll
  for (int d = 0; d < 4; d++) { xaf[d] = b2f(xa[d]); xmf[d] = b2f(xm[d]); }
  union { uint4 v4[2]; u16 h[16]; } wq, wk, wv;
  const uint4* wqp = reinterpret_cast<const uint4*>(Wqkv + nph * 16);
  const uint4* wkp = reinterpret_cast<const uint4*>(Wqkv + 10752 + nph * 16);
  const uint4* wvp = reinterpret_cast<const uint4*>(Wqkv + 21504 + nph * 16);
  wq.v4[0] = wqp[0]; wq.v4[1] = wqp[1];
  wk.v4[0] = wkp[0]; wk.v4[1] = wkp[1];
  wv.v4[0] = wvp[0]; wv.v4[1] = wvp[1];
  u16 qo[4], ko[4], vo[4];
#pragma unroll
  for (int o = 0; o < 4; o++) {
    float aq = 0.f, ak = 0.f, av = 0.f;
#pragma unroll
    for (int d = 0; d < 4; d++) {
      aq += xaf[d] * b2f(wq.h[d * 4 + o]);
      ak += xaf[d] * b2f(wk.h[d * 4 + o]);
      av += xmf[d] * b2f(wv.h[d * 4 + o]);
    }
    qo[o] = f2b(aq); ko[o] = f2b(ak); vo[o] = f2b(av);
  }
  long ob = bs * HH + cbase;
  *reinterpret_cast<uint2*>(q + ob) = *reinterpret_cast<uint2*>(qo);
  *reinterpret_cast<uint2*>(k + ob) = *reinterpret_cast<uint2*>(ko);
  *reinterpret_cast<uint2*>(v + ob) = *reinterpret_cast<uint2*>(vo);
}

// ---------------------------------------------------------------------------
// per (b,n): ipre/fpre from G (12288x24) + bias; cs=cumsum(logsig(f));
// a=i-cs; rmax=prefmax(a); m=cs+rmax
__global__ __launch_bounds__(1024) void scan_kernel(
    const float* __restrict__ G, const float* __restrict__ big,
    const float* __restrict__ bfg,
    float* __restrict__ avec, float* __restrict__ rmaxvec, float* __restrict__ mvec)
{
  __shared__ float buf[2][SS];
  __shared__ float isave[SS];
  __shared__ float cssave[SS];
  int bn = blockIdx.x;
  int b = bn >> 2, n = bn & 3;
  int t = threadIdx.x;
  float bi = big[n], bf = bfg[n];
  for (int i = t; i < SS; i += 1024) {
    long tk = (long)b * SS + i;
    float ip = G[tk * 24 + n] + G[(4096 + tk) * 24 + 8 + n] +
               G[(8192 + tk) * 24 + 16 + n] + bi;
    float fp = G[tk * 24 + 4 + n] + G[(4096 + tk) * 24 + 12 + n] +
               G[(8192 + tk) * 24 + 20 + n] + bf;
    isave[i] = ip;
    buf[0][i] = logsig_f(fp);
  }
  __syncthreads();
  int src = 0;
  for (int off = 1; off < SS; off <<= 1) {
    int dst = 1 - src;
    for (int i = t; i < SS; i += 1024) {
      float x = buf[src][i];
      if (i >= off) x += buf[src][i - off];
      buf[dst][i] = x;
    }
    __syncthreads();
    src = dst;
  }
  for (int i = t; i < SS; i += 1024) {
    float cs = buf[src][i];
    cssave[i] = cs;
    float a = isave[i] - cs;
    avec[(long)bn * SS + i] = a;
    buf[src][i] = a;
  }
  __syncthreads();
  for (int off = 1; off < SS; off <<= 1) {
    int dst = 1 - src;
    for (int i = t; i < SS; i += 1024) {
      float x = buf[src][i];
      if (i >= off) x = fmaxf(x, buf[src][i - off]);
      buf[dst][i] = x;
    }
    __syncthreads();
    src = dst;
  }
  for (int i = t; i < SS; i += 1024) {
    rmaxvec[(long)bn * SS + i] = buf[src][i];
    mvec[(long)bn * SS + i] = cssave[i] + buf[src][i];
  }
}

// ---------------------------------------------------------------------------
// causal row sums of P -> inv_n
__global__ __launch_bounds__(256) void rowsum_kernel(
    const u16* __restrict__ P, const float* __restrict__ mvec, float* __restrict__ invn,
    long Pstride)
{
  int bz = blockIdx.z;
  P += (long)bz * Pstride;
  mvec += (long)bz * SS;
  invn += (long)bz * SS;
  int row = (blockIdx.x * 256 + threadIdx.x) >> 6;
  int lane = threadIdx.x & 63;
  if (row >= SS) return;
  const u16* pr = P + (long)row * SS;
  float s = 0.f;
  for (int j = lane; j <= row; j += 64) s += b2f(pr[j]);
#pragma unroll
  for (int off = 32; off > 0; off >>= 1) s += __shfl_down(s, off);
  if (lane == 0) {
    float n = fmaxf(fabsf(s), __expf(-mvec[row]));
    invn[row] = 1.f / (n + 1e-6f);
  }
}

// ---------------------------------------------------------------------------
__global__ __launch_bounds__(256) void ln_skip_gate(
    const u16* __restrict__ h, const u16* __restrict__ xca,
    const u16* __restrict__ xinner, const float* __restrict__ normw,
    const float* __restrict__ skipw, u16* __restrict__ hs)
{
  int row = (blockIdx.x * 256 + threadIdx.x) >> 6;  // (b*NH+n)*S + s
  int lane = threadIdx.x & 63;
  if (row >= BB * NHH * SS) return;
  int s = row % SS;
  int n = (row / SS) % NHH;
  int b = row / (SS * NHH);
  const u16* hr = h + (long)row * DHH;
  float sum = 0.f, ss = 0.f;
  float vals[11];
  int cnt = 0;
  for (int d = lane; d < DHH; d += 64) {
    float x = b2f(hr[d]);
    vals[cnt++] = x; sum += x; ss += x * x;
  }
#pragma unroll
  for (int off = 32; off > 0; off >>= 1) { sum += __shfl_down(sum, off); ss += __shfl_down(ss, off); }
  sum = __shfl(sum, 0); ss = __shfl(ss, 0);
  float mu = sum / (float)DHH;
  float var = ss / (float)DHH - mu * mu;
  float rstd = rsqrtf(var + 1e-5f);
  long bs = (long)b * SS + s;
  cnt = 0;
  for (int d = lane; d < DHH; d += 64) {
    int c = n * DHH + d;
    float hn = (vals[cnt++] - mu) * rstd * normw[c];
    float hskip = hn + skipw[c] * b2f(xca[bs * HH + c]);
    float z = b2f(xinner[bs * H2 + HH + c]);
    hs[bs * HH + c] = f2b(hskip * silu_f(z));
  }
}

// ---------------------------------------------------------------------------
__global__ __launch_bounds__(256) void fill_sentinel(float* out, float v, long n) {
  long i = (long)blockIdx.x * 256 + threadIdx.x;
  if (i < n) out[i] = v;
}

// ---------------------------------------------------------------------------
extern "C" void kernel_launch(void* const* d_in, const int* in_sizes, int n_in,
                              void* d_out, int out_size, void* d_ws, size_t ws_size,
                              hipStream_t stream)
{
  const float* x      = (const float*)d_in[0];
  const float* W_in   = (const float*)d_in[1];
  const float* conv_w = (const float*)d_in[2];
  const float* conv_b = (const float*)d_in[3];
  const float* Wq     = (const float*)d_in[4];
  const float* Wk     = (const float*)d_in[5];
  const float* Wv     = (const float*)d_in[6];
  const float* W_ig   = (const float*)d_in[7];
  const float* b_ig   = (const float*)d_in[8];
  const float* W_fg   = (const float*)d_in[9];
  const float* b_fg   = (const float*)d_in[10];
  const float* norm_w = (const float*)d_in[11];
  const float* skipw  = (const float*)d_in[12];
  const float* W_out  = (const float*)d_in[13];
  float* out = (float*)d_out;
  const long SD = (long)SS * DHH;     // head slice elems
  const long SP = (long)SS * SS;
  const long BH = (long)SS * HH;      // per-batch elems of (S,H)

  u16* ws = (u16*)d_ws;
  size_t off = 0;
  auto alloc = [&](size_t n) { u16* p = ws + off; off += n; return p; };
  u16* x_inner = alloc((size_t)4096 * H2);
  u16* xca     = alloc((size_t)4096 * HH);
  u16* qb      = alloc((size_t)4096 * HH);   // W_inT -> q -> hs
  u16* kb      = alloc((size_t)4096 * HH);   // xbf -> k -> h
  u16* vb      = alloc((size_t)4096 * HH);   // v -> W_outT
  float* fvec  = (float*)(ws + off);
  off += 4 * 16384 * 2;
  float* avec    = fvec;
  float* rmaxvec = avec + 16384;
  float* mvec    = rmaxvec + 16384;
  float* invn    = mvec + 16384;
  u16* vt8 = alloc((size_t)8 * SD);
  u16* Pb8 = alloc((size_t)8 * SP);
  size_t need = off * 2;
  long outn = (long)4096 * EE;

  if (ws_size < need) {
    fill_sentinel<<<dim3((outn + 255) / 256), 256, 0, stream>>>(
        out, 200.f + 0.01f * (float)(ws_size >> 20), outn);
    return;
  }

  // overlays
  u16* W_inT  = qb;                       // consumed before headwise writes q
  u16* xbf    = kb;                       // consumed before headwise writes k
  u16* W_outT = vb;                       // written after v's last use
  u16* hbuf   = kb;                       // h (bn,S,DH) after k's last use
  u16* hsbuf  = qb;                       // hs after q's last use
  u16* WT3    = Pb8;                      // 128x2688, consumed before QK
  float* G    = (float*)(Pb8 + 344064);   // 12288x24 fp32, consumed before QK
  u16* Wqkv   = Pb8 + 933888;             // 3x10752, consumed before QK

  prep_wt3<<<dim3(1344, 1, 1), 256, 0, stream>>>(W_ig, W_fg, WT3);
  prep_wqkv<<<dim3(126, 1, 1), 256, 0, stream>>>(Wq, Wk, Wv, Wqkv);
  transpose_any<1><<<dim3(84, 32, 1), 256, 0, stream>>>(
      W_in, W_inT, EE, H2, H2, 0, 0, 0);
  convert_x<<<dim3(4096, 1, 1), 256, 0, stream>>>(x, xbf);
  // x_inner = x @ W_in : M=4096 N=5376 K=2048, deep-pipelined 128x256 tiles
  gemm_nt2<0, 0><<<dim3(21, 32, 1), 512, 0, stream>>>(
      xbf, W_inT, x_inner, 4096, H2, EE, EE, EE, H2,
      0, 0, 0, 0, 0, 0, nullptr, nullptr, 0, 0);
  conv_silu<<<dim3(10752, 1, 1), 256, 0, stream>>>(x_inner, conv_w, conv_b, xca);
  headwise_qkv<<<dim3(10752, 1, 1), 256, 0, stream>>>(
      x_inner, xca, Wqkv, qb, kb, vb);
  // gates: [q;k;v] (12288 x 2688) @ WT3^T -> G (12288 x 24) — old kernel (N=24)
  gemm_nt<0, 1><<<dim3(1, 96, 1), 256, 0, stream>>>(
      qb, WT3, G, 12288, 24, HH, HH, HH, 24,
      0, 0, 0, 0, 0, 0, nullptr, nullptr, 0, 0);
  scan_kernel<<<dim3(8, 1, 1), 1024, 0, stream>>>(G, b_ig, b_fg, avec, rmaxvec, mvec);
  // v^T per (b,n): (DH, S)
  transpose_any<0><<<dim3(11, 32, 8), 256, 0, stream>>>(
      vb, vt8, SS, DHH, HH, BH, DHH, SD);
  // P = (q k^T / sqrt(DH)) * exp(a[col]-rmax[row]), causal
  gemm_nt2<1, 0><<<dim3(8, 16, 8), 512, 0, stream>>>(
      qb, kb, Pb8, SS, SS, DHH, HH, HH, SS,
      BH, DHH, BH, DHH, 4 * SP, SP, avec, rmaxvec, SS, 0);
  rowsum_kernel<<<dim3(512, 1, 8), 256, 0, stream>>>(Pb8, mvec, invn, SP);
  // h = (P @ v) * inv_n, into (bn, S, DH); B over-reads rows 672..767 into Pb8
  // region (in-bounds garbage, masked by col<N guard)
  gemm_nt2<2, 0><<<dim3(3, 16, 8), 512, 0, stream>>>(
      Pb8, vt8, hbuf, SS, DHH, SS, SS, SS, DHH,
      4 * SP, SP, 4 * SD, SD, 4 * SD, SD, invn, nullptr, SS, 1);
  transpose_any<1><<<dim3(32, 42, 1), 256, 0, stream>>>(
      W_out, W_outT, HH, EE, EE, 0, 0, 0);
  ln_skip_gate<<<dim3(4096, 1, 1), 256, 0, stream>>>(
      hbuf, xca, x_inner, norm_w, skipw, hsbuf);
  gemm_nt2<0, 1><<<dim3(8, 32, 1), 512, 0, stream>>>(
      hsbuf, W_outT, out, 4096, EE, HH, HH, HH, EE,
      0, 0, 0, 0, 0, 0, nullptr, nullptr, 0, 0);
}

// Round 2
// 702.188 us; speedup vs baseline: 1.0538x; 1.0173x over previous
//
#include <hip/hip_runtime.h>

typedef unsigned short u16;
typedef unsigned int u32;
typedef __bf16 bf16x8 __attribute__((ext_vector_type(8)));
typedef float f32x4 __attribute__((ext_vector_type(4)));

#define BB   2
#define SS   2048
#define EE   2048
#define HH   2688
#define NHH  4
#define DHH  672
#define NPHH 672
#define H2   5376
#define H3   8064

__device__ __forceinline__ float b2f(u16 u) {
  union { unsigned int i; float f; } c; c.i = ((unsigned int)u) << 16; return c.f;
}
__device__ __forceinline__ u16 f2b(float f) {
  union { float f; unsigned int i; } c; c.f = f;
  unsigned int i = c.i;
  return (u16)((i + 0x7FFFu + ((i >> 16) & 1u)) >> 16);
}
__device__ __forceinline__ float silu_f(float x) { return x / (1.f + __expf(-x)); }
__device__ __forceinline__ float logsig_f(float f) {
  return (f >= 0.f) ? -log1pf(__expf(-f)) : (f - log1pf(__expf(f)));
}

// async global->LDS, 16B per lane; dst wave-uniform base, HW adds lane*16B
__device__ __forceinline__ void gl2lds16(const u16* g, u16* s) {
  __builtin_amdgcn_global_load_lds(
      (const __attribute__((address_space(1))) u32*)g,
      (__attribute__((address_space(3))) u32*)s, 16, 0, 0);
}

template <int N> __device__ __forceinline__ void vmwait() {
  asm volatile("s_waitcnt vmcnt(%0)" :: "n"(N) : "memory");
}

// ---------------------------------------------------------------------------
// Phase-interleaved NT GEMM (bf16): C[i,j] = sum_k A[i,k]*Bt[j,k]
// BM x 256 tile, BK=32, 8 waves (2M x 4N), 4-deep LDS ring, stage lead = 3.
// Each K-tile is split into NPH = BM/64 phases:
//   { ds_read 2 A-frags (+4 B-frags in phase 0) | stage 1 chunk of tile t+3 |
//     s_barrier | lgkmcnt(0) | sched_barrier | setprio(1) 8 MFMA setprio(0) }
// so LDS reads of phase p overlap MFMA execution of phase p-1 across waves
// (m201 structure). Counted vmcnt only at tile boundaries (never 0 mid-loop).
// Safety: every phase drains its own ds_reads (lgkm(0)) before its MFMAs, so
// at each tile-end barrier no LDS reads are in flight -> staging into slot
// (t+3)&3 == (t-1)&3 is WAR-safe. vmcnt FIFO is per-wave (each wave stages
// its own slice) and tile-end barrier makes all waves' staging visible.
// MODE 0 plain; MODE 1 QK epilogue (skip above-diag blocks);
// MODE 2 PV epilogue (row scale, causal K-cap). OUTF32: fp32 store.
// Requires: M % BM == 0, K % 32 == 0. N bounds-checked on store; B staging
// may over-read up to 255 rows past N (callers guarantee in-bounds memory).
// ---------------------------------------------------------------------------
template <int BM, int MODE, int OUTF32>
__global__ __launch_bounds__(512, 1) void gemm_p(
    const u16* __restrict__ A, const u16* __restrict__ Bt, void* __restrict__ Cp,
    int M, int N, int K, int lda, int ldb, int ldc,
    long sAhi, long sAlo, long sBhi, long sBlo, long sChi, long sClo,
    const float* __restrict__ aux1, const float* __restrict__ aux2,
    int auxStride, int causal)
{
  constexpr int MFR   = BM / 32;          // m-frags per wave (4 or 8)
  constexpr int NPH   = MFR / 2;          // phases per K-tile (2 or 4)
  constexpr int SLOT  = (BM + 256) * 32;  // u16 per ring slot
  constexpr int ACH   = BM / 128;         // A stage chunks (1 or 2)
  constexpr int LOADS = ACH + 2;          // gl2lds per thread per tile (3 or 4)
  __shared__ __align__(16) u16 sm[4 * SLOT];

  // bijective XCD-aware block swizzle
  int gx = gridDim.x;
  int nwg = gx * gridDim.y;
  int flat = blockIdx.y * gx + blockIdx.x;
  int qq = nwg >> 3, r8 = nwg & 7;
  int xcd = flat & 7, seq = flat >> 3;
  int logical = (xcd < r8 ? xcd * (qq + 1) : r8 * (qq + 1) + (xcd - r8) * qq) + seq;
  int bx = logical % gx, by = logical / gx;
  int m0 = by * BM, n0 = bx * 256;
  if (MODE == 1 && n0 > m0 + BM - 1) return;

  int bz = blockIdx.z, bzh = bz >> 2, bzl = bz & 3;
  A  += bzh * sAhi + bzl * sAlo;
  Bt += bzh * sBhi + bzl * sBlo;
  const float* a1 = aux1 ? aux1 + (long)bz * auxStride : nullptr;
  const float* a2 = aux2 ? aux2 + (long)bz * auxStride : nullptr;
  u16*   C16 = (u16*)Cp + bzh * sChi + bzl * sClo;
  float* C32 = (float*)Cp + bzh * sChi + bzl * sClo;

  int t = threadIdx.x, lane = t & 63, w = t >> 6;
  int l15 = lane & 15, quad = lane >> 4;
  int wr = w >> 2, wc = w & 3;   // wave -> (M half, N quarter)

  // --- staging setup: 512 threads cover 128 rows x 32 cols per chunk ---
  // pre-swizzled global source: physical chunk (t&3) at row (t>>2) receives
  // logical chunk (t&3)^((row>>1)&3)  (involution; matches read side)
  int srow = t >> 2;                              // 0..127 within chunk
  int swz = (((t & 3) ^ ((t >> 3) & 3)) * 8);
  const u16* pS[LOADS];
  int coff[LOADS];
#pragma unroll
  for (int c = 0; c < ACH; ++c) {
    pS[c] = A + (long)(m0 + c * 128 + srow) * lda + swz;
    coff[c] = c * 4096 + w * 512;
  }
#pragma unroll
  for (int c = 0; c < 2; ++c) {
    pS[ACH + c] = Bt + (long)(n0 + c * 128 + srow) * ldb + swz;
    coff[ACH + c] = BM * 32 + c * 4096 + w * 512;
  }

  // --- read offsets (u16 units), same swizzle involution ---
  int rswz = (quad ^ ((l15 >> 1) & 3)) * 8;
  int aoff = (wr * (BM / 2) + l15) * 32 + rswz;          // + i*512 per m-frag
  int boff = BM * 32 + (wc * 64 + l15) * 32 + rswz;      // + j*512 per n-frag

  f32x4 acc[MFR][4];
#pragma unroll
  for (int i = 0; i < MFR; i++)
#pragma unroll
    for (int j = 0; j < 4; j++) acc[i][j] = (f32x4){0.f, 0.f, 0.f, 0.f};

  int Keff = (MODE == 2 && causal) ? min(K, m0 + BM) : K;
  int T = Keff >> 5;

  auto STAGE1 = [&](int tt, int c) {
    gl2lds16(pS[c] + (tt << 5), sm + (tt & 3) * SLOT + coff[c]);
  };

  // prologue: stage tiles 0..2, wait for tile 0 only
  int npre = T < 3 ? T : 3;
  for (int tt = 0; tt < npre; ++tt)
#pragma unroll
    for (int c = 0; c < LOADS; ++c) STAGE1(tt, c);
  if (npre >= 3)      vmwait<2 * LOADS>();
  else if (npre == 2) vmwait<LOADS>();
  else                vmwait<0>();
  __builtin_amdgcn_s_barrier();
  __builtin_amdgcn_sched_barrier(0);

  for (int tq = 0; tq < T; ++tq) {
    u16* Sb = sm + (tq & 3) * SLOT;
    const bool stg = (tq + 3 < T);
    bf16x8 bf[4];
#pragma unroll
    for (int p = 0; p < NPH; ++p) {
      bf16x8 a0 = *reinterpret_cast<const bf16x8*>(Sb + aoff + (2 * p) * 512);
      bf16x8 a1v = *reinterpret_cast<const bf16x8*>(Sb + aoff + (2 * p + 1) * 512);
      if (p == 0) {
#pragma unroll
        for (int j = 0; j < 4; ++j)
          bf[j] = *reinterpret_cast<const bf16x8*>(Sb + boff + j * 512);
      }
      if (stg) {
#pragma unroll
        for (int c = p * LOADS / NPH; c < (p + 1) * LOADS / NPH; ++c)
          STAGE1(tq + 3, c);
      }
      __builtin_amdgcn_s_barrier();
      asm volatile("s_waitcnt lgkmcnt(0)" ::: "memory");
      __builtin_amdgcn_sched_barrier(0);
      __builtin_amdgcn_s_setprio(1);
#pragma unroll
      for (int j = 0; j < 4; ++j)
        acc[2 * p][j] = __builtin_amdgcn_mfma_f32_16x16x32_bf16(a0, bf[j], acc[2 * p][j], 0, 0, 0);
#pragma unroll
      for (int j = 0; j < 4; ++j)
        acc[2 * p + 1][j] = __builtin_amdgcn_mfma_f32_16x16x32_bf16(a1v, bf[j], acc[2 * p + 1][j], 0, 0, 0);
      __builtin_amdgcn_s_setprio(0);
      __builtin_amdgcn_sched_barrier(0);
    }
    // tile boundary: ensure tile tq+1's staging complete; keep newer in flight
    if (tq + 1 < T) {
      if (tq + 3 < T)      vmwait<2 * LOADS>();
      else if (tq + 2 < T) vmwait<LOADS>();
      else                 vmwait<0>();
      __builtin_amdgcn_s_barrier();
      __builtin_amdgcn_sched_barrier(0);
    }
  }

  const float rs = 0.03857583749f;  // 1/sqrt(672)
#pragma unroll
  for (int i = 0; i < MFR; i++) {
#pragma unroll
    for (int j = 0; j < 4; j++) {
      int col = n0 + wc * 64 + j * 16 + l15;
      if (col >= N) continue;
#pragma unroll
      for (int rr = 0; rr < 4; rr++) {
        int row = m0 + wr * (BM / 2) + i * 16 + quad * 4 + rr;
        if (row >= M) continue;
        float v = acc[i][j][rr];
        if (MODE == 1) v = (col <= row) ? v * rs * __expf(a1[col] - a2[row]) : 0.f;
        else if (MODE == 2) v = v * a1[row];
        if (OUTF32) C32[(long)row * ldc + col] = v;
        else        C16[(long)row * ldc + col] = f2b(v);
      }
    }
  }
}

// ---------------------------------------------------------------------------
// transpose with row stride: out[c*R + r] = in[r*ldin + c]; F32IN: fp32 source
// ---------------------------------------------------------------------------
template <int F32IN>
__global__ __launch_bounds__(256) void transpose_any(
    const void* __restrict__ in, u16* __restrict__ out, int R, int C, int ldin,
    long inHi, long inLo, long outStride)
{
  __shared__ u16 tile[64][65];
  int bz = blockIdx.z, bzh = bz >> 2, bzl = bz & 3;
  const u16* in16 = (const u16*)in + bzh * inHi + bzl * inLo;
  const float* inf = (const float*)in + bzh * inHi + bzl * inLo;
  out += (long)bz * outStride;
  int r0 = blockIdx.y * 64, c0 = blockIdx.x * 64;
  int t = threadIdx.x;
  for (int idx = t; idx < 64 * 64; idx += 256) {
    int r = idx >> 6, c = idx & 63;
    int rr = r0 + r, cc = c0 + c;
    u16 v = 0;
    if (rr < R && cc < C) {
      long off = (long)rr * ldin + cc;
      v = F32IN ? f2b(inf[off]) : in16[off];
    }
    tile[r][c] = v;
  }
  __syncthreads();
  for (int idx = t; idx < 64 * 64; idx += 256) {
    int r = idx & 63, c = idx >> 6;
    int rr = r0 + r, cc = c0 + c;
    if (rr < R && cc < C) out[(long)cc * R + rr] = tile[r][c];
  }
}

// ---------------------------------------------------------------------------
// x fp32 -> bf16, 8/thread
__global__ __launch_bounds__(256) void convert_x(
    const float* __restrict__ x, u16* __restrict__ o)
{
  long i = ((long)blockIdx.x * 256 + threadIdx.x) * 8;
  if (i >= (long)4096 * EE) return;
  float4 a = *reinterpret_cast<const float4*>(x + i);
  float4 b = *reinterpret_cast<const float4*>(x + i + 4);
  u16 t8[8] = {f2b(a.x), f2b(a.y), f2b(a.z), f2b(a.w),
               f2b(b.x), f2b(b.y), f2b(b.z), f2b(b.w)};
  *reinterpret_cast<uint4*>(o + i) = *reinterpret_cast<uint4*>(t8);
}

// ---------------------------------------------------------------------------
// WT3 (128 x 2688 bf16): rows r<24: r=seg*8+j -> (j<4?W_ig:W_fg)[seg*H + c, j&3]
__global__ __launch_bounds__(256) void prep_wt3(
    const float* __restrict__ Wig, const float* __restrict__ Wfg,
    u16* __restrict__ WT3)
{
  int i = blockIdx.x * 256 + threadIdx.x;
  if (i >= 128 * HH) return;
  int r = i / HH, c = i % HH;
  float v = 0.f;
  if (r < 24) {
    int seg = r >> 3, j = r & 7;
    const float* W = (j < 4) ? Wig : Wfg;
    v = W[(long)(seg * HH + c) * 4 + (j & 3)];
  }
  WT3[i] = f2b(v);
}

// Wq|Wk|Wv fp32 -> bf16 packed (3 x 10752)
__global__ __launch_bounds__(256) void prep_wqkv(
    const float* __restrict__ Wq, const float* __restrict__ Wk,
    const float* __restrict__ Wv, u16* __restrict__ o)
{
  int i = blockIdx.x * 256 + threadIdx.x;
  if (i >= 3 * 10752) return;
  int m = i / 10752, j = i % 10752;
  const float* W = (m == 0) ? Wq : (m == 1) ? Wk : Wv;
  o[i] = f2b(W[j]);
}

// ---------------------------------------------------------------------------
// depthwise causal conv (KS=4) + bias + silu, 4 h/thread
__global__ __launch_bounds__(256) void conv_silu(
    const u16* __restrict__ xinner, const float* __restrict__ cw,
    const float* __restrict__ cb, u16* __restrict__ xca)
{
  long idx = (long)blockIdx.x * 256 + threadIdx.x;
  if (idx >= (long)BB * SS * HH / 4) return;
  int h4 = (int)(idx % (HH / 4)) * 4;
  long bs = idx / (HH / 4);
  int s = (int)(bs % SS);
  float4 acc = *reinterpret_cast<const float4*>(cb + h4);
#pragma unroll
  for (int w = 0; w < 4; w++) {
    int sp = s + w - 3;
    if (sp < 0) continue;
    uint2 xr = *reinterpret_cast<const uint2*>(xinner + (bs + w - 3) * H2 + h4);
    const u16* xh = (const u16*)&xr;
    float4 cwv = *reinterpret_cast<const float4*>(cw + w * HH + h4);
    acc.x += b2f(xh[0]) * cwv.x;
    acc.y += b2f(xh[1]) * cwv.y;
    acc.z += b2f(xh[2]) * cwv.z;
    acc.w += b2f(xh[3]) * cwv.w;
  }
  u16 o4[4] = {f2b(silu_f(acc.x)), f2b(silu_f(acc.y)),
               f2b(silu_f(acc.z)), f2b(silu_f(acc.w))};
  *reinterpret_cast<uint2*>(xca + bs * HH + h4) = *reinterpret_cast<uint2*>(o4);
}

// ---------------------------------------------------------------------------
// headwise 4x4 projections, outputs stay in (B,S,H) layout (no relayout)
__global__ __launch_bounds__(256) void headwise_qkv(
    const u16* __restrict__ xinner, const u16* __restrict__ xca,
    const u16* __restrict__ Wqkv,
    u16* __restrict__ q, u16* __restrict__ k, u16* __restrict__ v)
{
  int idx = blockIdx.x * 256 + threadIdx.x;
  if (idx >= BB * SS * NPHH) return;
  int nph = idx % NPHH;
  long bs = idx / NPHH;
  int cbase = nph * 4;
  uint2 xar = *reinterpret_cast<const uint2*>(xca + bs * HH + cbase);
  uint2 xmr = *reinterpret_cast<const uint2*>(xinner + bs * H2 + cbase);
  const u16* xa = (const u16*)&xar;
  const u16* xm = (const u16*)&xmr;
  float xaf[4], xmf[4];
#pragma unroll
  for (int d = 0; d < 4; d++) { xaf[d] = b2f(xa[d]); xmf[d] = b2f(xm[d]); }
  union { uint4 v4[2]; u16 h[16]; } wq, wk, wv;
  const uint4* wqp = reinterpret_cast<const uint4*>(Wqkv + nph * 16);
  const uint4* wkp = reinterpret_cast<const uint4*>(Wqkv + 10752 + nph * 16);
  const uint4* wvp = reinterpret_cast<const uint4*>(Wqkv + 21504 + nph * 16);
  wq.v4[0] = wqp[0]; wq.v4[1] = wqp[1];
  wk.v4[0] = wkp[0]; wk.v4[1] = wkp[1];
  wv.v4[0] = wvp[0]; wv.v4[1] = wvp[1];
  u16 qo[4], ko[4], vo[4];
#pragma unroll
  for (int o = 0; o < 4; o++) {
    float aq = 0.f, ak = 0.f, av = 0.f;
#pragma unroll
    for (int d = 0; d < 4; d++) {
      aq += xaf[d] * b2f(wq.h[d * 4 + o]);
      ak += xaf[d] * b2f(wk.h[d * 4 + o]);
      av += xmf[d] * b2f(wv.h[d * 4 + o]);
    }
    qo[o] = f2b(aq); ko[o] = f2b(ak); vo[o] = f2b(av);
  }
  long ob = bs * HH + cbase;
  *reinterpret_cast<uint2*>(q + ob) = *reinterpret_cast<uint2*>(qo);
  *reinterpret_cast<uint2*>(k + ob) = *reinterpret_cast<uint2*>(ko);
  *reinterpret_cast<uint2*>(v + ob) = *reinterpret_cast<uint2*>(vo);
}

// ---------------------------------------------------------------------------
// per (b,n): ipre/fpre from G (12288x24) + bias; cs=cumsum(logsig(f));
// a=i-cs; rmax=prefmax(a); m=cs+rmax
__global__ __launch_bounds__(1024) void scan_kernel(
    const float* __restrict__ G, const float* __restrict__ big,
    const float* __restrict__ bfg,
    float* __restrict__ avec, float* __restrict__ rmaxvec, float* __restrict__ mvec)
{
  __shared__ float buf[2][SS];
  __shared__ float isave[SS];
  __shared__ float cssave[SS];
  int bn = blockIdx.x;
  int b = bn >> 2, n = bn & 3;
  int t = threadIdx.x;
  float bi = big[n], bf = bfg[n];
  for (int i = t; i < SS; i += 1024) {
    long tk = (long)b * SS + i;
    float ip = G[tk * 24 + n] + G[(4096 + tk) * 24 + 8 + n] +
               G[(8192 + tk) * 24 + 16 + n] + bi;
    float fp = G[tk * 24 + 4 + n] + G[(4096 + tk) * 24 + 12 + n] +
               G[(8192 + tk) * 24 + 20 + n] + bf;
    isave[i] = ip;
    buf[0][i] = logsig_f(fp);
  }
  __syncthreads();
  int src = 0;
  for (int off = 1; off < SS; off <<= 1) {
    int dst = 1 - src;
    for (int i = t; i < SS; i += 1024) {
      float x = buf[src][i];
      if (i >= off) x += buf[src][i - off];
      buf[dst][i] = x;
    }
    __syncthreads();
    src = dst;
  }
  for (int i = t; i < SS; i += 1024) {
    float cs = buf[src][i];
    cssave[i] = cs;
    float a = isave[i] - cs;
    avec[(long)bn * SS + i] = a;
    buf[src][i] = a;
  }
  __syncthreads();
  for (int off = 1; off < SS; off <<= 1) {
    int dst = 1 - src;
    for (int i = t; i < SS; i += 1024) {
      float x = buf[src][i];
      if (i >= off) x = fmaxf(x, buf[src][i - off]);
      buf[dst][i] = x;
    }
    __syncthreads();
    src = dst;
  }
  for (int i = t; i < SS; i += 1024) {
    rmaxvec[(long)bn * SS + i] = buf[src][i];
    mvec[(long)bn * SS + i] = cssave[i] + buf[src][i];
  }
}

// ---------------------------------------------------------------------------
// causal row sums of P -> inv_n
__global__ __launch_bounds__(256) void rowsum_kernel(
    const u16* __restrict__ P, const float* __restrict__ mvec, float* __restrict__ invn,
    long Pstride)
{
  int bz = blockIdx.z;
  P += (long)bz * Pstride;
  mvec += (long)bz * SS;
  invn += (long)bz * SS;
  int row = (blockIdx.x * 256 + threadIdx.x) >> 6;
  int lane = threadIdx.x & 63;
  if (row >= SS) return;
  const u16* pr = P + (long)row * SS;
  float s = 0.f;
  for (int j = lane; j <= row; j += 64) s += b2f(pr[j]);
#pragma unroll
  for (int off = 32; off > 0; off >>= 1) s += __shfl_down(s, off);
  if (lane == 0) {
    float n = fmaxf(fabsf(s), __expf(-mvec[row]));
    invn[row] = 1.f / (n + 1e-6f);
  }
}

// ---------------------------------------------------------------------------
__global__ __launch_bounds__(256) void ln_skip_gate(
    const u16* __restrict__ h, const u16* __restrict__ xca,
    const u16* __restrict__ xinner, const float* __restrict__ normw,
    const float* __restrict__ skipw, u16* __restrict__ hs)
{
  int row = (blockIdx.x * 256 + threadIdx.x) >> 6;  // (b*NH+n)*S + s
  int lane = threadIdx.x & 63;
  if (row >= BB * NHH * SS) return;
  int s = row % SS;
  int n = (row / SS) % NHH;
  int b = row / (SS * NHH);
  const u16* hr = h + (long)row * DHH;
  float sum = 0.f, ss = 0.f;
  float vals[11];
  int cnt = 0;
  for (int d = lane; d < DHH; d += 64) {
    float x = b2f(hr[d]);
    vals[cnt++] = x; sum += x; ss += x * x;
  }
#pragma unroll
  for (int off = 32; off > 0; off >>= 1) { sum += __shfl_down(sum, off); ss += __shfl_down(ss, off); }
  sum = __shfl(sum, 0); ss = __shfl(ss, 0);
  float mu = sum / (float)DHH;
  float var = ss / (float)DHH - mu * mu;
  float rstd = rsqrtf(var + 1e-5f);
  long bs = (long)b * SS + s;
  cnt = 0;
  for (int d = lane; d < DHH; d += 64) {
    int c = n * DHH + d;
    float hn = (vals[cnt++] - mu) * rstd * normw[c];
    float hskip = hn + skipw[c] * b2f(xca[bs * HH + c]);
    float z = b2f(xinner[bs * H2 + HH + c]);
    hs[bs * HH + c] = f2b(hskip * silu_f(z));
  }
}

// ---------------------------------------------------------------------------
__global__ __launch_bounds__(256) void fill_sentinel(float* out, float v, long n) {
  long i = (long)blockIdx.x * 256 + threadIdx.x;
  if (i < n) out[i] = v;
}

// ---------------------------------------------------------------------------
extern "C" void kernel_launch(void* const* d_in, const int* in_sizes, int n_in,
                              void* d_out, int out_size, void* d_ws, size_t ws_size,
                              hipStream_t stream)
{
  const float* x      = (const float*)d_in[0];
  const float* W_in   = (const float*)d_in[1];
  const float* conv_w = (const float*)d_in[2];
  const float* conv_b = (const float*)d_in[3];
  const float* Wq     = (const float*)d_in[4];
  const float* Wk     = (const float*)d_in[5];
  const float* Wv     = (const float*)d_in[6];
  const float* W_ig   = (const float*)d_in[7];
  const float* b_ig   = (const float*)d_in[8];
  const float* W_fg   = (const float*)d_in[9];
  const float* b_fg   = (const float*)d_in[10];
  const float* norm_w = (const float*)d_in[11];
  const float* skipw  = (const float*)d_in[12];
  const float* W_out  = (const float*)d_in[13];
  float* out = (float*)d_out;
  const long SD = (long)SS * DHH;     // head slice elems
  const long SP = (long)SS * SS;
  const long BH = (long)SS * HH;      // per-batch elems of (S,H)

  u16* ws = (u16*)d_ws;
  size_t off = 0;
  auto alloc = [&](size_t n) { u16* p = ws + off; off += n; return p; };
  u16* x_inner = alloc((size_t)4096 * H2);
  u16* xca     = alloc((size_t)4096 * HH);
  u16* qb      = alloc((size_t)4096 * HH);   // W_inT -> q -> hs
  u16* kb      = alloc((size_t)4096 * HH);   // xbf -> k -> h
  u16* vb      = alloc((size_t)4096 * HH);   // v -> W_outT
  float* fvec  = (float*)(ws + off);
  off += 4 * 16384 * 2;
  float* avec    = fvec;
  float* rmaxvec = avec + 16384;
  float* mvec    = rmaxvec + 16384;
  float* invn    = mvec + 16384;
  u16* vt8 = alloc((size_t)8 * SD);
  u16* Pb8 = alloc((size_t)8 * SP);
  size_t need = off * 2;
  long outn = (long)4096 * EE;

  if (ws_size < need) {
    fill_sentinel<<<dim3((outn + 255) / 256), 256, 0, stream>>>(
        out, 200.f + 0.01f * (float)(ws_size >> 20), outn);
    return;
  }

  // overlays
  u16* W_inT  = qb;                       // consumed before headwise writes q
  u16* xbf    = kb;                       // consumed before headwise writes k
  u16* W_outT = vb;                       // written after v's last use
  u16* hbuf   = kb;                       // h (bn,S,DH) after k's last use
  u16* hsbuf  = qb;                       // hs after q's last use
  u16* WT3    = Pb8;                      // 128x2688, consumed before QK
  float* G    = (float*)(Pb8 + 344064);   // 12288x24 fp32, consumed before QK
  u16* Wqkv   = Pb8 + 933888;             // 3x10752, consumed before QK

  prep_wt3<<<dim3(1344, 1, 1), 256, 0, stream>>>(W_ig, W_fg, WT3);
  prep_wqkv<<<dim3(126, 1, 1), 256, 0, stream>>>(Wq, Wk, Wv, Wqkv);
  transpose_any<1><<<dim3(84, 32, 1), 256, 0, stream>>>(
      W_in, W_inT, EE, H2, H2, 0, 0, 0);
  convert_x<<<dim3(4096, 1, 1), 256, 0, stream>>>(x, xbf);
  // x_inner = x @ W_in : M=4096 N=5376 K=2048 (256x256 tiles, 336 blocks)
  gemm_p<256, 0, 0><<<dim3(21, 16, 1), 512, 0, stream>>>(
      xbf, W_inT, x_inner, 4096, H2, EE, EE, EE, H2,
      0, 0, 0, 0, 0, 0, nullptr, nullptr, 0, 0);
  conv_silu<<<dim3(10752, 1, 1), 256, 0, stream>>>(x_inner, conv_w, conv_b, xca);
  headwise_qkv<<<dim3(10752, 1, 1), 256, 0, stream>>>(
      x_inner, xca, Wqkv, qb, kb, vb);
  // gates: [q;k;v] (12288 x 2688) @ WT3^T -> G (12288 x 24)
  // (B staging over-reads WT3 rows 128..255 into Pb8 region; cols masked)
  gemm_p<128, 0, 1><<<dim3(1, 96, 1), 512, 0, stream>>>(
      qb, WT3, G, 12288, 24, HH, HH, HH, 24,
      0, 0, 0, 0, 0, 0, nullptr, nullptr, 0, 0);
  scan_kernel<<<dim3(8, 1, 1), 1024, 0, stream>>>(G, b_ig, b_fg, avec, rmaxvec, mvec);
  // v^T per (b,n): (DH, S)
  transpose_any<0><<<dim3(11, 32, 8), 256, 0, stream>>>(
      vb, vt8, SS, DHH, HH, BH, DHH, SD);
  // P = (q k^T / sqrt(DH)) * exp(a[col]-rmax[row]), causal (256x256 tiles)
  gemm_p<256, 1, 0><<<dim3(8, 8, 8), 512, 0, stream>>>(
      qb, kb, Pb8, SS, SS, DHH, HH, HH, SS,
      BH, DHH, BH, DHH, 4 * SP, SP, avec, rmaxvec, SS, 0);
  rowsum_kernel<<<dim3(512, 1, 8), 256, 0, stream>>>(Pb8, mvec, invn, SP);
  // h = (P @ v) * inv_n, into (bn, S, DH); B over-reads rows 672..767 into
  // Pb8 region (in-bounds garbage, masked by col<N guard)
  gemm_p<128, 2, 0><<<dim3(3, 16, 8), 512, 0, stream>>>(
      Pb8, vt8, hbuf, SS, DHH, SS, SS, SS, DHH,
      4 * SP, SP, 4 * SD, SD, 4 * SD, SD, invn, nullptr, SS, 1);
  transpose_any<1><<<dim3(32, 42, 1), 256, 0, stream>>>(
      W_out, W_outT, HH, EE, EE, 0, 0, 0);
  ln_skip_gate<<<dim3(4096, 1, 1), 256, 0, stream>>>(
      hbuf, xca, x_inner, norm_w, skipw, hsbuf);
  gemm_p<128, 0, 1><<<dim3(8, 32, 1), 512, 0, stream>>>(
      hsbuf, W_outT, out, 4096, EE, HH, HH, HH, EE,
      0, 0, 0, 0, 0, 0, nullptr, nullptr, 0, 0);
}

// Round 3
// 661.842 us; speedup vs baseline: 1.1180x; 1.0610x over previous
//
#include <hip/hip_runtime.h>

typedef unsigned short u16;
typedef unsigned int u32;
typedef __bf16 bf16x8 __attribute__((ext_vector_type(8)));
typedef float f32x4 __attribute__((ext_vector_type(4)));

#define BB   2
#define SS   2048
#define EE   2048
#define HH   2688
#define NHH  4
#define DHH  672
#define NPHH 672
#define H2   5376
#define H3   8064

__device__ __forceinline__ float b2f(u16 u) {
  union { unsigned int i; float f; } c; c.i = ((unsigned int)u) << 16; return c.f;
}
__device__ __forceinline__ u16 f2b(float f) {
  union { float f; unsigned int i; } c; c.f = f;
  unsigned int i = c.i;
  return (u16)((i + 0x7FFFu + ((i >> 16) & 1u)) >> 16);
}
__device__ __forceinline__ float silu_f(float x) { return x / (1.f + __expf(-x)); }
__device__ __forceinline__ float logsig_f(float f) {
  return (f >= 0.f) ? -log1pf(__expf(-f)) : (f - log1pf(__expf(f)));
}

// async global->LDS, 16B per lane; dst wave-uniform base, HW adds lane*16B
__device__ __forceinline__ void gl2lds16(const u16* g, u16* s) {
  __builtin_amdgcn_global_load_lds(
      (const __attribute__((address_space(1))) u32*)g,
      (__attribute__((address_space(3))) u32*)s, 16, 0, 0);
}

template <int N> __device__ __forceinline__ void vmwait() {
  asm volatile("s_waitcnt vmcnt(%0)" :: "n"(N) : "memory");
}

// ---------------------------------------------------------------------------
// gemm8: m201-style 2-phase NT GEMM (bf16): C[i,j] = sum_k A[i,k]*Bt[j,k]
// 128x256 tile, BK=64, 8 waves (2M x 4N), ring-3 LDS (3 x 48KB = 144 KiB),
// prefetch lead 2 tiles, vmcnt(6) once per tile (never 0 mid-loop).
// Per K-64 tile, 2 phases; each phase:
//   { ds_read frags (ph0: 4 A + 8 B held in regs; ph1: 4 A) |
//     3x global_load_lds of tile t+2 | s_barrier | lgkmcnt(0) |
//     setprio(1) 16 MFMA setprio(0) | s_barrier }
// LDS rows are 64 cols (128 B) -> naive frag read = 32-way bank conflict;
// fixed by XOR involution on 16B chunks: phys_chunk = logical ^ (row & 7),
// applied on BOTH the pre-swizzled global source and the ds_read address.
// WAR safety: tile t-1's reads all drained (lgkm(0) before its MFMAs) before
// its trailing barrier; staging of t+2 (slot (t+2)%3 == (t-1)%3) is issued
// after that barrier. vmcnt FIFO per-wave; tile-end barrier publishes LDS.
// MODE 0 plain; MODE 2 PV epilogue (row scale, causal K-cap). OUTF32: fp32.
// Requires: M % 128 == 0, K % 64 == 0. N masked on store; B staging may
// over-read up to 255 rows past N (callers guarantee in-bounds memory).
// ---------------------------------------------------------------------------
template <int MODE, int OUTF32>
__global__ __launch_bounds__(512, 1) void gemm8(
    const u16* __restrict__ A, const u16* __restrict__ Bt, void* __restrict__ Cp,
    int M, int N, int K, int lda, int ldb, int ldc,
    long sAhi, long sAlo, long sBhi, long sBlo, long sChi, long sClo,
    const float* __restrict__ aux1, const float* __restrict__ aux2,
    int auxStride, int causal)
{
  constexpr int SLOT = (128 + 256) * 64;   // u16 per ring slot (48 KiB)
  __shared__ __align__(16) u16 sm[3 * SLOT];  // 144 KiB

  // bijective XCD-aware block swizzle
  int gx = gridDim.x;
  int nwg = gx * gridDim.y;
  int flat = blockIdx.y * gx + blockIdx.x;
  int qq = nwg >> 3, r8 = nwg & 7;
  int xcd = flat & 7, seq = flat >> 3;
  int logical = (xcd < r8 ? xcd * (qq + 1) : r8 * (qq + 1) + (xcd - r8) * qq) + seq;
  int bx = logical % gx, by = logical / gx;
  int m0 = by * 128, n0 = bx * 256;
  if (MODE == 1 && n0 > m0 + 127) return;

  int bz = blockIdx.z, bzh = bz >> 2, bzl = bz & 3;
  A  += bzh * sAhi + bzl * sAlo;
  Bt += bzh * sBhi + bzl * sBlo;
  const float* a1 = aux1 ? aux1 + (long)bz * auxStride : nullptr;
  const float* a2 = aux2 ? aux2 + (long)bz * auxStride : nullptr;
  u16*   C16 = (u16*)Cp + bzh * sChi + bzl * sClo;
  float* C32 = (float*)Cp + bzh * sChi + bzl * sClo;

  int t = threadIdx.x, lane = t & 63, w = t >> 6;
  int l15 = lane & 15, quad = lane >> 4;
  int wr = w >> 2, wc = w & 3;   // wave -> (M half, N quarter)

  // staging: thread t covers (row = t>>3 within 64-row chunk, chunk16 = t&7);
  // pre-swizzle global source col by chunk ^ (row&7)
  int srow = t >> 3;
  int sw8 = ((t & 7) ^ (srow & 7)) * 8;
  const u16* pS[6];
  int dOf[6];
#pragma unroll
  for (int c = 0; c < 2; ++c) {           // A chunks: rows c*64..c*64+63
    pS[c] = A + (long)(m0 + c * 64 + srow) * lda + sw8;
    dOf[c] = c * 4096 + w * 512;
  }
#pragma unroll
  for (int c = 0; c < 4; ++c) {           // B chunks: rows c*64..c*64+63
    pS[2 + c] = Bt + (long)(n0 + c * 64 + srow) * ldb + sw8;
    dOf[2 + c] = 8192 + c * 4096 + w * 512;
  }

  f32x4 acc[4][4];
#pragma unroll
  for (int i = 0; i < 4; i++)
#pragma unroll
    for (int j = 0; j < 4; j++) acc[i][j] = (f32x4){0.f, 0.f, 0.f, 0.f};

  int Keff = (MODE == 2 && causal) ? min(K, m0 + 128) : K;
  int T = Keff >> 6;                       // K-64 tiles

  auto STAGE = [&](int slot, int k2, int c) {
    gl2lds16(pS[c] + k2, sm + slot * SLOT + dOf[c]);
  };

  // prologue: stage tiles 0 (and 1), wait for tile 0 only
  int npre = T < 2 ? T : 2;
  for (int tt = 0; tt < npre; ++tt)
#pragma unroll
    for (int c = 0; c < 6; ++c) STAGE(tt, tt << 6, c);
  if (npre >= 2) vmwait<6>(); else vmwait<0>();
  __builtin_amdgcn_s_barrier();
  __builtin_amdgcn_sched_barrier(0);

  int sl = 0;
  for (int tq = 0; tq < T; ++tq) {
    u16* Sb = sm + sl * SLOT;
    int sl2 = sl + 2; if (sl2 >= 3) sl2 -= 3;
    const bool stg = (tq + 2 < T);
    const int k2 = (tq + 2) << 6;
    int cx = (l15 & 7);                    // row&7 for this lane's frag rows

    // ---- phase 0: all B frags + A frags i=0,1 ----
    bf16x8 bfr[4][2], af[2][2];
#pragma unroll
    for (int j = 0; j < 4; ++j)
#pragma unroll
      for (int ks = 0; ks < 2; ++ks)
        bfr[j][ks] = *reinterpret_cast<const bf16x8*>(
            Sb + 8192 + (wc * 64 + j * 16 + l15) * 64 + ((((ks << 2) + quad) ^ cx) << 3));
#pragma unroll
    for (int i = 0; i < 2; ++i)
#pragma unroll
      for (int ks = 0; ks < 2; ++ks)
        af[i][ks] = *reinterpret_cast<const bf16x8*>(
            Sb + (wr * 64 + i * 16 + l15) * 64 + ((((ks << 2) + quad) ^ cx) << 3));
    if (stg) { STAGE(sl2, k2, 0); STAGE(sl2, k2, 1); STAGE(sl2, k2, 2); }
    __builtin_amdgcn_s_barrier();
    asm volatile("s_waitcnt lgkmcnt(0)" ::: "memory");
    __builtin_amdgcn_sched_barrier(0);
    __builtin_amdgcn_s_setprio(1);
#pragma unroll
    for (int i = 0; i < 2; ++i)
#pragma unroll
      for (int j = 0; j < 4; ++j) {
        acc[i][j] = __builtin_amdgcn_mfma_f32_16x16x32_bf16(af[i][0], bfr[j][0], acc[i][j], 0, 0, 0);
        acc[i][j] = __builtin_amdgcn_mfma_f32_16x16x32_bf16(af[i][1], bfr[j][1], acc[i][j], 0, 0, 0);
      }
    __builtin_amdgcn_s_setprio(0);
    __builtin_amdgcn_sched_barrier(0);
    __builtin_amdgcn_s_barrier();

    // ---- phase 1: A frags i=2,3 (B held in regs) ----
    bf16x8 ag[2][2];
#pragma unroll
    for (int i = 0; i < 2; ++i)
#pragma unroll
      for (int ks = 0; ks < 2; ++ks)
        ag[i][ks] = *reinterpret_cast<const bf16x8*>(
            Sb + (wr * 64 + (i + 2) * 16 + l15) * 64 + ((((ks << 2) + quad) ^ cx) << 3));
    if (stg) { STAGE(sl2, k2, 3); STAGE(sl2, k2, 4); STAGE(sl2, k2, 5); }
    __builtin_amdgcn_s_barrier();
    asm volatile("s_waitcnt lgkmcnt(0)" ::: "memory");
    __builtin_amdgcn_sched_barrier(0);
    __builtin_amdgcn_s_setprio(1);
#pragma unroll
    for (int i = 0; i < 2; ++i)
#pragma unroll
      for (int j = 0; j < 4; ++j) {
        acc[i + 2][j] = __builtin_amdgcn_mfma_f32_16x16x32_bf16(ag[i][0], bfr[j][0], acc[i + 2][j], 0, 0, 0);
        acc[i + 2][j] = __builtin_amdgcn_mfma_f32_16x16x32_bf16(ag[i][1], bfr[j][1], acc[i + 2][j], 0, 0, 0);
      }
    __builtin_amdgcn_s_setprio(0);
    __builtin_amdgcn_sched_barrier(0);
    if (tq + 1 < T) {
      if (stg) vmwait<6>(); else vmwait<0>();
      __builtin_amdgcn_s_barrier();
      __builtin_amdgcn_sched_barrier(0);
    }
    sl = sl + 1; if (sl >= 3) sl = 0;
  }

  const float rs = 0.03857583749f;  // 1/sqrt(672)
#pragma unroll
  for (int i = 0; i < 4; i++) {
#pragma unroll
    for (int j = 0; j < 4; j++) {
      int col = n0 + wc * 64 + j * 16 + l15;
      if (col >= N) continue;
#pragma unroll
      for (int rr = 0; rr < 4; rr++) {
        int row = m0 + wr * 64 + i * 16 + quad * 4 + rr;
        if (row >= M) continue;
        float v = acc[i][j][rr];
        if (MODE == 1) v = (col <= row) ? v * rs * __expf(a1[col] - a2[row]) : 0.f;
        else if (MODE == 2) v = v * a1[row];
        if (OUTF32) C32[(long)row * ldc + col] = v;
        else        C16[(long)row * ldc + col] = f2b(v);
      }
    }
  }
}

// ---------------------------------------------------------------------------
// Phase-interleaved NT GEMM (bf16), BK=32 — kept for QK (K=672 % 64 != 0).
// ---------------------------------------------------------------------------
template <int BM, int MODE, int OUTF32>
__global__ __launch_bounds__(512, 1) void gemm_p(
    const u16* __restrict__ A, const u16* __restrict__ Bt, void* __restrict__ Cp,
    int M, int N, int K, int lda, int ldb, int ldc,
    long sAhi, long sAlo, long sBhi, long sBlo, long sChi, long sClo,
    const float* __restrict__ aux1, const float* __restrict__ aux2,
    int auxStride, int causal)
{
  constexpr int MFR   = BM / 32;          // m-frags per wave (4 or 8)
  constexpr int NPH   = MFR / 2;          // phases per K-tile (2 or 4)
  constexpr int SLOT  = (BM + 256) * 32;  // u16 per ring slot
  constexpr int ACH   = BM / 128;         // A stage chunks (1 or 2)
  constexpr int LOADS = ACH + 2;          // gl2lds per thread per tile (3 or 4)
  __shared__ __align__(16) u16 sm[4 * SLOT];

  int gx = gridDim.x;
  int nwg = gx * gridDim.y;
  int flat = blockIdx.y * gx + blockIdx.x;
  int qq = nwg >> 3, r8 = nwg & 7;
  int xcd = flat & 7, seq = flat >> 3;
  int logical = (xcd < r8 ? xcd * (qq + 1) : r8 * (qq + 1) + (xcd - r8) * qq) + seq;
  int bx = logical % gx, by = logical / gx;
  int m0 = by * BM, n0 = bx * 256;
  if (MODE == 1 && n0 > m0 + BM - 1) return;

  int bz = blockIdx.z, bzh = bz >> 2, bzl = bz & 3;
  A  += bzh * sAhi + bzl * sAlo;
  Bt += bzh * sBhi + bzl * sBlo;
  const float* a1 = aux1 ? aux1 + (long)bz * auxStride : nullptr;
  const float* a2 = aux2 ? aux2 + (long)bz * auxStride : nullptr;
  u16*   C16 = (u16*)Cp + bzh * sChi + bzl * sClo;
  float* C32 = (float*)Cp + bzh * sChi + bzl * sClo;

  int t = threadIdx.x, lane = t & 63, w = t >> 6;
  int l15 = lane & 15, quad = lane >> 4;
  int wr = w >> 2, wc = w & 3;

  int srow = t >> 2;
  int swz = (((t & 3) ^ ((t >> 3) & 3)) * 8);
  const u16* pS[LOADS];
  int coff[LOADS];
#pragma unroll
  for (int c = 0; c < ACH; ++c) {
    pS[c] = A + (long)(m0 + c * 128 + srow) * lda + swz;
    coff[c] = c * 4096 + w * 512;
  }
#pragma unroll
  for (int c = 0; c < 2; ++c) {
    pS[ACH + c] = Bt + (long)(n0 + c * 128 + srow) * ldb + swz;
    coff[ACH + c] = BM * 32 + c * 4096 + w * 512;
  }

  int rswz = (quad ^ ((l15 >> 1) & 3)) * 8;
  int aoff = (wr * (BM / 2) + l15) * 32 + rswz;
  int boff = BM * 32 + (wc * 64 + l15) * 32 + rswz;

  f32x4 acc[MFR][4];
#pragma unroll
  for (int i = 0; i < MFR; i++)
#pragma unroll
    for (int j = 0; j < 4; j++) acc[i][j] = (f32x4){0.f, 0.f, 0.f, 0.f};

  int Keff = (MODE == 2 && causal) ? min(K, m0 + BM) : K;
  int T = Keff >> 5;

  auto STAGE1 = [&](int tt, int c) {
    gl2lds16(pS[c] + (tt << 5), sm + (tt & 3) * SLOT + coff[c]);
  };

  int npre = T < 3 ? T : 3;
  for (int tt = 0; tt < npre; ++tt)
#pragma unroll
    for (int c = 0; c < LOADS; ++c) STAGE1(tt, c);
  if (npre >= 3)      vmwait<2 * LOADS>();
  else if (npre == 2) vmwait<LOADS>();
  else                vmwait<0>();
  __builtin_amdgcn_s_barrier();
  __builtin_amdgcn_sched_barrier(0);

  for (int tq = 0; tq < T; ++tq) {
    u16* Sb = sm + (tq & 3) * SLOT;
    const bool stg = (tq + 3 < T);
    bf16x8 bf[4];
#pragma unroll
    for (int p = 0; p < NPH; ++p) {
      bf16x8 a0 = *reinterpret_cast<const bf16x8*>(Sb + aoff + (2 * p) * 512);
      bf16x8 a1v = *reinterpret_cast<const bf16x8*>(Sb + aoff + (2 * p + 1) * 512);
      if (p == 0) {
#pragma unroll
        for (int j = 0; j < 4; ++j)
          bf[j] = *reinterpret_cast<const bf16x8*>(Sb + boff + j * 512);
      }
      if (stg) {
#pragma unroll
        for (int c = p * LOADS / NPH; c < (p + 1) * LOADS / NPH; ++c)
          STAGE1(tq + 3, c);
      }
      __builtin_amdgcn_s_barrier();
      asm volatile("s_waitcnt lgkmcnt(0)" ::: "memory");
      __builtin_amdgcn_sched_barrier(0);
      __builtin_amdgcn_s_setprio(1);
#pragma unroll
      for (int j = 0; j < 4; ++j)
        acc[2 * p][j] = __builtin_amdgcn_mfma_f32_16x16x32_bf16(a0, bf[j], acc[2 * p][j], 0, 0, 0);
#pragma unroll
      for (int j = 0; j < 4; ++j)
        acc[2 * p + 1][j] = __builtin_amdgcn_mfma_f32_16x16x32_bf16(a1v, bf[j], acc[2 * p + 1][j], 0, 0, 0);
      __builtin_amdgcn_s_setprio(0);
      __builtin_amdgcn_sched_barrier(0);
    }
    if (tq + 1 < T) {
      if (tq + 3 < T)      vmwait<2 * LOADS>();
      else if (tq + 2 < T) vmwait<LOADS>();
      else                 vmwait<0>();
      __builtin_amdgcn_s_barrier();
      __builtin_amdgcn_sched_barrier(0);
    }
  }

  const float rs = 0.03857583749f;  // 1/sqrt(672)
#pragma unroll
  for (int i = 0; i < MFR; i++) {
#pragma unroll
    for (int j = 0; j < 4; j++) {
      int col = n0 + wc * 64 + j * 16 + l15;
      if (col >= N) continue;
#pragma unroll
      for (int rr = 0; rr < 4; rr++) {
        int row = m0 + wr * (BM / 2) + i * 16 + quad * 4 + rr;
        if (row >= M) continue;
        float v = acc[i][j][rr];
        if (MODE == 1) v = (col <= row) ? v * rs * __expf(a1[col] - a2[row]) : 0.f;
        else if (MODE == 2) v = v * a1[row];
        if (OUTF32) C32[(long)row * ldc + col] = v;
        else        C16[(long)row * ldc + col] = f2b(v);
      }
    }
  }
}

// ---------------------------------------------------------------------------
// transpose with row stride: out[c*R + r] = in[r*ldin + c]; F32IN: fp32 source
// ---------------------------------------------------------------------------
template <int F32IN>
__global__ __launch_bounds__(256) void transpose_any(
    const void* __restrict__ in, u16* __restrict__ out, int R, int C, int ldin,
    long inHi, long inLo, long outStride)
{
  __shared__ u16 tile[64][65];
  int bz = blockIdx.z, bzh = bz >> 2, bzl = bz & 3;
  const u16* in16 = (const u16*)in + bzh * inHi + bzl * inLo;
  const float* inf = (const float*)in + bzh * inHi + bzl * inLo;
  out += (long)bz * outStride;
  int r0 = blockIdx.y * 64, c0 = blockIdx.x * 64;
  int t = threadIdx.x;
  for (int idx = t; idx < 64 * 64; idx += 256) {
    int r = idx >> 6, c = idx & 63;
    int rr = r0 + r, cc = c0 + c;
    u16 v = 0;
    if (rr < R && cc < C) {
      long off = (long)rr * ldin + cc;
      v = F32IN ? f2b(inf[off]) : in16[off];
    }
    tile[r][c] = v;
  }
  __syncthreads();
  for (int idx = t; idx < 64 * 64; idx += 256) {
    int r = idx & 63, c = idx >> 6;
    int rr = r0 + r, cc = c0 + c;
    if (rr < R && cc < C) out[(long)cc * R + rr] = tile[r][c];
  }
}

// ---------------------------------------------------------------------------
// x fp32 -> bf16, 8/thread
__global__ __launch_bounds__(256) void convert_x(
    const float* __restrict__ x, u16* __restrict__ o)
{
  long i = ((long)blockIdx.x * 256 + threadIdx.x) * 8;
  if (i >= (long)4096 * EE) return;
  float4 a = *reinterpret_cast<const float4*>(x + i);
  float4 b = *reinterpret_cast<const float4*>(x + i + 4);
  u16 t8[8] = {f2b(a.x), f2b(a.y), f2b(a.z), f2b(a.w),
               f2b(b.x), f2b(b.y), f2b(b.z), f2b(b.w)};
  *reinterpret_cast<uint4*>(o + i) = *reinterpret_cast<uint4*>(t8);
}

// ---------------------------------------------------------------------------
// WT3 (128 x 2688 bf16): rows r<24: r=seg*8+j -> (j<4?W_ig:W_fg)[seg*H + c, j&3]
__global__ __launch_bounds__(256) void prep_wt3(
    const float* __restrict__ Wig, const float* __restrict__ Wfg,
    u16* __restrict__ WT3)
{
  int i = blockIdx.x * 256 + threadIdx.x;
  if (i >= 128 * HH) return;
  int r = i / HH, c = i % HH;
  float v = 0.f;
  if (r < 24) {
    int seg = r >> 3, j = r & 7;
    const float* W = (j < 4) ? Wig : Wfg;
    v = W[(long)(seg * HH + c) * 4 + (j & 3)];
  }
  WT3[i] = f2b(v);
}

// Wq|Wk|Wv fp32 -> bf16 packed (3 x 10752)
__global__ __launch_bounds__(256) void prep_wqkv(
    const float* __restrict__ Wq, const float* __restrict__ Wk,
    const float* __restrict__ Wv, u16* __restrict__ o)
{
  int i = blockIdx.x * 256 + threadIdx.x;
  if (i >= 3 * 10752) return;
  int m = i / 10752, j = i % 10752;
  const float* W = (m == 0) ? Wq : (m == 1) ? Wk : Wv;
  o[i] = f2b(W[j]);
}

// ---------------------------------------------------------------------------
// depthwise causal conv (KS=4) + bias + silu, 4 h/thread
__global__ __launch_bounds__(256) void conv_silu(
    const u16* __restrict__ xinner, const float* __restrict__ cw,
    const float* __restrict__ cb, u16* __restrict__ xca)
{
  long idx = (long)blockIdx.x * 256 + threadIdx.x;
  if (idx >= (long)BB * SS * HH / 4) return;
  int h4 = (int)(idx % (HH / 4)) * 4;
  long bs = idx / (HH / 4);
  int s = (int)(bs % SS);
  float4 acc = *reinterpret_cast<const float4*>(cb + h4);
#pragma unroll
  for (int w = 0; w < 4; w++) {
    int sp = s + w - 3;
    if (sp < 0) continue;
    uint2 xr = *reinterpret_cast<const uint2*>(xinner + (bs + w - 3) * H2 + h4);
    const u16* xh = (const u16*)&xr;
    float4 cwv = *reinterpret_cast<const float4*>(cw + w * HH + h4);
    acc.x += b2f(xh[0]) * cwv.x;
    acc.y += b2f(xh[1]) * cwv.y;
    acc.z += b2f(xh[2]) * cwv.z;
    acc.w += b2f(xh[3]) * cwv.w;
  }
  u16 o4[4] = {f2b(silu_f(acc.x)), f2b(silu_f(acc.y)),
               f2b(silu_f(acc.z)), f2b(silu_f(acc.w))};
  *reinterpret_cast<uint2*>(xca + bs * HH + h4) = *reinterpret_cast<uint2*>(o4);
}

// ---------------------------------------------------------------------------
// headwise 4x4 projections, outputs stay in (B,S,H) layout (no relayout)
__global__ __launch_bounds__(256) void headwise_qkv(
    const u16* __restrict__ xinner, const u16* __restrict__ xca,
    const u16* __restrict__ Wqkv,
    u16* __restrict__ q, u16* __restrict__ k, u16* __restrict__ v)
{
  int idx = blockIdx.x * 256 + threadIdx.x;
  if (idx >= BB * SS * NPHH) return;
  int nph = idx % NPHH;
  long bs = idx / NPHH;
  int cbase = nph * 4;
  uint2 xar = *reinterpret_cast<const uint2*>(xca + bs * HH + cbase);
  uint2 xmr = *reinterpret_cast<const uint2*>(xinner + bs * H2 + cbase);
  const u16* xa = (const u16*)&xar;
  const u16* xm = (const u16*)&xmr;
  float xaf[4], xmf[4];
#pragma unroll
  for (int d = 0; d < 4; d++) { xaf[d] = b2f(xa[d]); xmf[d] = b2f(xm[d]); }
  union { uint4 v4[2]; u16 h[16]; } wq, wk, wv;
  const uint4* wqp = reinterpret_cast<const uint4*>(Wqkv + nph * 16);
  const uint4* wkp = reinterpret_cast<const uint4*>(Wqkv + 10752 + nph * 16);
  const uint4* wvp = reinterpret_cast<const uint4*>(Wqkv + 21504 + nph * 16);
  wq.v4[0] = wqp[0]; wq.v4[1] = wqp[1];
  wk.v4[0] = wkp[0]; wk.v4[1] = wkp[1];
  wv.v4[0] = wvp[0]; wv.v4[1] = wvp[1];
  u16 qo[4], ko[4], vo[4];
#pragma unroll
  for (int o = 0; o < 4; o++) {
    float aq = 0.f, ak = 0.f, av = 0.f;
#pragma unroll
    for (int d = 0; d < 4; d++) {
      aq += xaf[d] * b2f(wq.h[d * 4 + o]);
      ak += xaf[d] * b2f(wk.h[d * 4 + o]);
      av += xmf[d] * b2f(wv.h[d * 4 + o]);
    }
    qo[o] = f2b(aq); ko[o] = f2b(ak); vo[o] = f2b(av);
  }
  long ob = bs * HH + cbase;
  *reinterpret_cast<uint2*>(q + ob) = *reinterpret_cast<uint2*>(qo);
  *reinterpret_cast<uint2*>(k + ob) = *reinterpret_cast<uint2*>(ko);
  *reinterpret_cast<uint2*>(v + ob) = *reinterpret_cast<uint2*>(vo);
}

// ---------------------------------------------------------------------------
// per (b,n): ipre/fpre from G (12288x24) + bias; cs=cumsum(logsig(f));
// a=i-cs; rmax=prefmax(a); m=cs+rmax
__global__ __launch_bounds__(1024) void scan_kernel(
    const float* __restrict__ G, const float* __restrict__ big,
    const float* __restrict__ bfg,
    float* __restrict__ avec, float* __restrict__ rmaxvec, float* __restrict__ mvec)
{
  __shared__ float buf[2][SS];
  __shared__ float isave[SS];
  __shared__ float cssave[SS];
  int bn = blockIdx.x;
  int b = bn >> 2, n = bn & 3;
  int t = threadIdx.x;
  float bi = big[n], bf = bfg[n];
  for (int i = t; i < SS; i += 1024) {
    long tk = (long)b * SS + i;
    float ip = G[tk * 24 + n] + G[(4096 + tk) * 24 + 8 + n] +
               G[(8192 + tk) * 24 + 16 + n] + bi;
    float fp = G[tk * 24 + 4 + n] + G[(4096 + tk) * 24 + 12 + n] +
               G[(8192 + tk) * 24 + 20 + n] + bf;
    isave[i] = ip;
    buf[0][i] = logsig_f(fp);
  }
  __syncthreads();
  int src = 0;
  for (int off = 1; off < SS; off <<= 1) {
    int dst = 1 - src;
    for (int i = t; i < SS; i += 1024) {
      float x = buf[src][i];
      if (i >= off) x += buf[src][i - off];
      buf[dst][i] = x;
    }
    __syncthreads();
    src = dst;
  }
  for (int i = t; i < SS; i += 1024) {
    float cs = buf[src][i];
    cssave[i] = cs;
    float a = isave[i] - cs;
    avec[(long)bn * SS + i] = a;
    buf[src][i] = a;
  }
  __syncthreads();
  for (int off = 1; off < SS; off <<= 1) {
    int dst = 1 - src;
    for (int i = t; i < SS; i += 1024) {
      float x = buf[src][i];
      if (i >= off) x = fmaxf(x, buf[src][i - off]);
      buf[dst][i] = x;
    }
    __syncthreads();
    src = dst;
  }
  for (int i = t; i < SS; i += 1024) {
    rmaxvec[(long)bn * SS + i] = buf[src][i];
    mvec[(long)bn * SS + i] = cssave[i] + buf[src][i];
  }
}

// ---------------------------------------------------------------------------
// causal row sums of P -> inv_n (vectorized uint4 + in-bounds scalar tail)
__global__ __launch_bounds__(256) void rowsum_kernel(
    const u16* __restrict__ P, const float* __restrict__ mvec, float* __restrict__ invn,
    long Pstride)
{
  int bz = blockIdx.z;
  P += (long)bz * Pstride;
  mvec += (long)bz * SS;
  invn += (long)bz * SS;
  int row = (blockIdx.x * 256 + threadIdx.x) >> 6;
  int lane = threadIdx.x & 63;
  if (row >= SS) return;
  const u16* pr = P + (long)row * SS;
  float s = 0.f;
  int j0 = lane * 8;
  for (; j0 + 7 <= row; j0 += 512) {
    uint4 u = *reinterpret_cast<const uint4*>(pr + j0);
    const u16* e = (const u16*)&u;
#pragma unroll
    for (int q = 0; q < 8; ++q) s += b2f(e[q]);
  }
  if (j0 <= row) {
    for (int q = 0; j0 + q <= row; ++q) s += b2f(pr[j0 + q]);
  }
#pragma unroll
  for (int off = 32; off > 0; off >>= 1) s += __shfl_down(s, off);
  if (lane == 0) {
    float n = fmaxf(fabsf(s), __expf(-mvec[row]));
    invn[row] = 1.f / (n + 1e-6f);
  }
}

// ---------------------------------------------------------------------------
// multi-head layernorm + skip + gate (paired u32 bf16 loads)
__global__ __launch_bounds__(256) void ln_skip_gate(
    const u16* __restrict__ h, const u16* __restrict__ xca,
    const u16* __restrict__ xinner, const float* __restrict__ normw,
    const float* __restrict__ skipw, u16* __restrict__ hs)
{
  int row = (blockIdx.x * 256 + threadIdx.x) >> 6;  // (b*NH+n)*S + s
  int lane = threadIdx.x & 63;
  if (row >= BB * NHH * SS) return;
  int s = row % SS;
  int n = (row / SS) % NHH;
  int b = row / (SS * NHH);
  const u16* hr = h + (long)row * DHH;
  float sum = 0.f, ss = 0.f;
  float vx[6], vy[6];
#pragma unroll
  for (int i = 0; i < 6; ++i) {
    int d2 = lane + i * 64;                 // u32 index; d = 2*d2
    float x = 0.f, y = 0.f;
    if (d2 < DHH / 2) {
      u32 u = *reinterpret_cast<const u32*>(hr + d2 * 2);
      x = b2f((u16)u); y = b2f((u16)(u >> 16));
    }
    vx[i] = x; vy[i] = y;
    sum += x + y; ss += x * x + y * y;
  }
#pragma unroll
  for (int off = 32; off > 0; off >>= 1) { sum += __shfl_down(sum, off); ss += __shfl_down(ss, off); }
  sum = __shfl(sum, 0); ss = __shfl(ss, 0);
  float mu = sum / (float)DHH;
  float var = ss / (float)DHH - mu * mu;
  float rstd = rsqrtf(var + 1e-5f);
  long bs = (long)b * SS + s;
#pragma unroll
  for (int i = 0; i < 6; ++i) {
    int d2 = lane + i * 64;
    if (d2 >= DHH / 2) continue;
    int c = n * DHH + d2 * 2;
    float2 nw = *reinterpret_cast<const float2*>(normw + c);
    float2 sw = *reinterpret_cast<const float2*>(skipw + c);
    u32 xcu = *reinterpret_cast<const u32*>(xca + bs * HH + c);
    u32 zu  = *reinterpret_cast<const u32*>(xinner + bs * H2 + HH + c);
    float h0 = (vx[i] - mu) * rstd * nw.x + sw.x * b2f((u16)xcu);
    float h1 = (vy[i] - mu) * rstd * nw.y + sw.y * b2f((u16)(xcu >> 16));
    float o0 = h0 * silu_f(b2f((u16)zu));
    float o1 = h1 * silu_f(b2f((u16)(zu >> 16)));
    u32 ou = (u32)f2b(o0) | ((u32)f2b(o1) << 16);
    *reinterpret_cast<u32*>(hs + bs * HH + c) = ou;
  }
}

// ---------------------------------------------------------------------------
__global__ __launch_bounds__(256) void fill_sentinel(float* out, float v, long n) {
  long i = (long)blockIdx.x * 256 + threadIdx.x;
  if (i < n) out[i] = v;
}

// ---------------------------------------------------------------------------
extern "C" void kernel_launch(void* const* d_in, const int* in_sizes, int n_in,
                              void* d_out, int out_size, void* d_ws, size_t ws_size,
                              hipStream_t stream)
{
  const float* x      = (const float*)d_in[0];
  const float* W_in   = (const float*)d_in[1];
  const float* conv_w = (const float*)d_in[2];
  const float* conv_b = (const float*)d_in[3];
  const float* Wq     = (const float*)d_in[4];
  const float* Wk     = (const float*)d_in[5];
  const float* Wv     = (const float*)d_in[6];
  const float* W_ig   = (const float*)d_in[7];
  const float* b_ig   = (const float*)d_in[8];
  const float* W_fg   = (const float*)d_in[9];
  const float* b_fg   = (const float*)d_in[10];
  const float* norm_w = (const float*)d_in[11];
  const float* skipw  = (const float*)d_in[12];
  const float* W_out  = (const float*)d_in[13];
  float* out = (float*)d_out;
  const long SD = (long)SS * DHH;     // head slice elems
  const long SP = (long)SS * SS;
  const long BH = (long)SS * HH;      // per-batch elems of (S,H)

  u16* ws = (u16*)d_ws;
  size_t off = 0;
  auto alloc = [&](size_t n) { u16* p = ws + off; off += n; return p; };
  u16* x_inner = alloc((size_t)4096 * H2);
  u16* xca     = alloc((size_t)4096 * HH);
  u16* qb      = alloc((size_t)4096 * HH);   // W_inT -> q -> hs
  u16* kb      = alloc((size_t)4096 * HH);   // xbf -> k -> h
  u16* vb      = alloc((size_t)4096 * HH);   // v -> W_outT
  float* fvec  = (float*)(ws + off);
  off += 4 * 16384 * 2;
  float* avec    = fvec;
  float* rmaxvec = avec + 16384;
  float* mvec    = rmaxvec + 16384;
  float* invn    = mvec + 16384;
  u16* vt8 = alloc((size_t)8 * SD);
  u16* Pb8 = alloc((size_t)8 * SP);
  size_t need = off * 2;
  long outn = (long)4096 * EE;

  if (ws_size < need) {
    fill_sentinel<<<dim3((outn + 255) / 256), 256, 0, stream>>>(
        out, 200.f + 0.01f * (float)(ws_size >> 20), outn);
    return;
  }

  // overlays
  u16* W_inT  = qb;                       // consumed before headwise writes q
  u16* xbf    = kb;                       // consumed before headwise writes k
  u16* W_outT = vb;                       // written after v's last use
  u16* hbuf   = kb;                       // h (bn,S,DH) after k's last use
  u16* hsbuf  = qb;                       // hs after q's last use
  u16* WT3    = Pb8;                      // 128x2688, consumed before QK
  float* G    = (float*)(Pb8 + 344064);   // 12288x24 fp32, consumed before QK
  u16* Wqkv   = Pb8 + 933888;             // 3x10752, consumed before QK

  prep_wt3<<<dim3(1344, 1, 1), 256, 0, stream>>>(W_ig, W_fg, WT3);
  prep_wqkv<<<dim3(126, 1, 1), 256, 0, stream>>>(Wq, Wk, Wv, Wqkv);
  transpose_any<1><<<dim3(84, 32, 1), 256, 0, stream>>>(
      W_in, W_inT, EE, H2, H2, 0, 0, 0);
  convert_x<<<dim3(4096, 1, 1), 256, 0, stream>>>(x, xbf);
  // x_inner = x @ W_in : M=4096 N=5376 K=2048 (128x256 tiles, 672 blocks)
  gemm8<0, 0><<<dim3(21, 32, 1), 512, 0, stream>>>(
      xbf, W_inT, x_inner, 4096, H2, EE, EE, EE, H2,
      0, 0, 0, 0, 0, 0, nullptr, nullptr, 0, 0);
  conv_silu<<<dim3(10752, 1, 1), 256, 0, stream>>>(x_inner, conv_w, conv_b, xca);
  headwise_qkv<<<dim3(10752, 1, 1), 256, 0, stream>>>(
      x_inner, xca, Wqkv, qb, kb, vb);
  // gates: [q;k;v] (12288 x 2688) @ WT3^T -> G (12288 x 24), K=2688=42*64
  // (B staging over-reads WT3 rows 128..255 into Pb8 region; cols masked)
  gemm8<0, 1><<<dim3(1, 96, 1), 512, 0, stream>>>(
      qb, WT3, G, 12288, 24, HH, HH, HH, 24,
      0, 0, 0, 0, 0, 0, nullptr, nullptr, 0, 0);
  scan_kernel<<<dim3(8, 1, 1), 1024, 0, stream>>>(G, b_ig, b_fg, avec, rmaxvec, mvec);
  // v^T per (b,n): (DH, S)
  transpose_any<0><<<dim3(11, 32, 8), 256, 0, stream>>>(
      vb, vt8, SS, DHH, HH, BH, DHH, SD);
  // P = (q k^T / sqrt(DH)) * exp(a[col]-rmax[row]), causal; K=672 -> BK32 path
  gemm_p<256, 1, 0><<<dim3(8, 8, 8), 512, 0, stream>>>(
      qb, kb, Pb8, SS, SS, DHH, HH, HH, SS,
      BH, DHH, BH, DHH, 4 * SP, SP, avec, rmaxvec, SS, 0);
  rowsum_kernel<<<dim3(512, 1, 8), 256, 0, stream>>>(Pb8, mvec, invn, SP);
  // h = (P @ v) * inv_n, into (bn, S, DH); Keff = m0+128 (mult of 64 ok);
  // B over-reads vt8 rows 672..767 (in-bounds garbage, masked by col<N)
  gemm8<2, 0><<<dim3(3, 16, 8), 512, 0, stream>>>(
      Pb8, vt8, hbuf, SS, DHH, SS, SS, SS, DHH,
      4 * SP, SP, 4 * SD, SD, 4 * SD, SD, invn, nullptr, SS, 1);
  transpose_any<1><<<dim3(32, 42, 1), 256, 0, stream>>>(
      W_out, W_outT, HH, EE, EE, 0, 0, 0);
  ln_skip_gate<<<dim3(4096, 1, 1), 256, 0, stream>>>(
      hbuf, xca, x_inner, norm_w, skipw, hsbuf);
  gemm8<0, 1><<<dim3(8, 32, 1), 512, 0, stream>>>(
      hsbuf, W_outT, out, 4096, EE, HH, HH, HH, EE,
      0, 0, 0, 0, 0, 0, nullptr, nullptr, 0, 0);
}